// Round 2
// 106.534 us; speedup vs baseline: 1.0091x; 1.0091x over previous
//
#include <hip/hip_runtime.h>

// KPN per-pixel 5x5 predicted convolution, channels-last fp32.
// out[b,h,w,c] = sum_{i,j} feat[b,h+i-2,w+j-2,c] * kernel[b,h,w,i*5+j] + bias[c]
//
// Round 9 = Round 8 resubmitted verbatim (R8 bench died to a container/infra
// failure, no compile or profile evidence of a kernel problem; OOB audit of
// async staging passed: weight max addr == kern element count exactly).
//
// Round 8 = Round 7 structure with VH 4 -> 8 (vertical halo amortization).
//  - R7 diagnosis: timed window = 2 poison fills (~84us, fixed) + kernel
//    (~22us). Kernel is LDS-throughput-bound: per wave 40 ds_read_b128
//    (feat, 12cyc ea) + ~52 merged read2/b32 (weights, 6cyc ea) = ~790 DS
//    cyc/wave -> ~51k DS cyc per CU = ~21us. Matches observation.
//  - Feat b128 reads dominate: tile of 8 feat rows serves only 4 output
//    rows (10 b128 per output row per thread). VH=8 stages 12 feat rows
//    for 8 output rows -> 7.5 b128/output-row (-25% of dominant DS term).
//    Weight reads are read-once + read2-merged already (invariant).
//  - LDS 80,896 B (12x36x32ch feat + 8x32x25 weights) -> exactly 2
//    blocks/CU (161,792 <= 163,840). DS-throughput regime tolerates the
//    occupancy drop (3->2 blocks); staging stays fully async.
//  - Async staging: 54 feat + 25 weight global_load_lds width=16 issues,
//    both exact multiples of 64 lanes (no tail clamp needed).
//  - Halo rows use CLAMPED addresses; edge blocks (block-uniform branch)
//    zero OOB LDS rows/cols post-barrier, as in R7.

#define BB 4
#define HH 256
#define WW 256
#define CC 32
#define KK 5
#define VH 8                    // output rows per block (was 4)
#define TW 32                   // tile width (pixels)
#define TPB 256
#define TROWS (VH + KK - 1)     // 12 feat rows
#define TCOLS (TW + KK - 1)     // 36 feat cols
#define SF_F4 (TROWS * TCOLS * CC / 4)   // 3456 float4 = 55.3 KB
#define SK_F4 (VH * TW * KK * KK / 4)    // 1600 float4 = 25.6 KB
#define NQF (SF_F4 / 64)        // 54 feat async issues
#define NQ  ((SF_F4 + SK_F4) / 64)       // 79 total issues

typedef __attribute__((address_space(1))) const void gvoid_t;
typedef __attribute__((address_space(3))) void svoid_t;

__global__ __launch_bounds__(TPB, 2) void kpn_conv_kernel(
    const float* __restrict__ feat,
    const float* __restrict__ kern,
    const float* __restrict__ bias,
    float* __restrict__ out)
{
    __shared__ float4 sb[SF_F4 + SK_F4];   // 80,896 B -> 2 blocks/CU

    const int t    = threadIdx.x;
    const int lane = t & 63;
    const int wave = t >> 6;

    const int bw = blockIdx.x & 7;            // W/TW = 8  (== XCD id: vertical
    const int bh = (blockIdx.x >> 3) & 31;    // H/VH = 32  neighbors share L2)
    const int b  = blockIdx.x >> 8;           // B = 4
    const int h0 = bh * VH;
    const int w0 = bw * TW;

    const float* fb = feat + (((size_t)b) << 16) * CC;
    const float* kb = kern + (size_t)((b * HH + h0) * WW + w0) * (KK * KK);

    // ---- Async staging: 79 wave-issues, all in flight, zero VGPR payload. ----
    for (int q = wave; q < NQ; q += TPB / 64) {
        if (q < NQF) {
            // feat: LDS float4 slot e = q*64+lane -> (row, col, c4)
            int e   = (q << 6) + lane;
            int row = e / (TCOLS * CC / 4);          // /288
            int rem = e - row * (TCOLS * CC / 4);
            int col = rem >> 3;
            int c4  = rem & 7;
            int hc  = min(max(h0 + row - (KK / 2), 0), HH - 1);
            int wc  = min(max(w0 + col - (KK / 2), 0), WW - 1);
            const float* gp = fb + ((((size_t)hc << 8) + wc) << 5) + (c4 << 2);
            __builtin_amdgcn_global_load_lds((gvoid_t*)gp,
                                             (svoid_t*)(sb + (q << 6)),
                                             16, 0, 0);
        } else {
            // weights: raw contiguous copy per output row (200 f4 per oh).
            int e   = ((q - NQF) << 6) + lane;       // 0..1599, exact fit
            int oh  = e / 200;
            int off = (e - oh * 200) << 2;
            const float* gp = kb + (size_t)oh * (WW * KK * KK) + off;
            __builtin_amdgcn_global_load_lds((gvoid_t*)gp,
                                             (svoid_t*)(sb + SF_F4 + ((q - NQF) << 6)),
                                             16, 0, 0);
        }
    }
    __syncthreads();   // drains vmcnt (covers global_load_lds)

    // ---- Edge blocks only: zero OOB halo entries (block-uniform branch). ----
    const bool wlo = (w0 == 0), whi = (w0 == WW - TW);
    if (h0 == 0 || h0 == HH - VH || wlo || whi) {
        const float4 z = make_float4(0.f, 0.f, 0.f, 0.f);
        #pragma unroll
        for (int r = 0; r < TROWS; ++r) {
            int hraw = h0 + r - (KK / 2);
            if (hraw < 0 || hraw >= HH) {            // uniform per block
                for (int s = t; s < TCOLS * CC / 4; s += TPB)   // 288 slots
                    sb[r * (TCOLS * CC / 4) + s] = z;
            }
        }
        if (wlo && t < 192) {   // cols 0,1: 12 rows x 2 cols x 8 f4
            int r = t >> 4, c = (t >> 3) & 1, c4 = t & 7;
            sb[r * (TCOLS * CC / 4) + c * 8 + c4] = z;
        }
        if (whi && t < 192) {   // cols 34,35
            int r = t >> 4, c = (TCOLS - 2) + ((t >> 3) & 1), c4 = t & 7;
            sb[r * (TCOLS * CC / 4) + c * 8 + c4] = z;
        }
        __syncthreads();
    }

    // ---- Maskless compute from LDS. ----
    const int cg = (t & 7) << 2;   // channel group
    const int wL = t >> 3;         // 0..31
    const float* sf  = (const float*)sb;
    const float* skw = (const float*)(sb + SF_F4);

    const float4 bz = *(const float4*)(bias + cg);
    float4 acc[VH];
    #pragma unroll
    for (int oh = 0; oh < VH; ++oh) acc[oh] = bz;

    #pragma unroll
    for (int r = 0; r < TROWS; ++r) {
        float4 f[KK];
        #pragma unroll
        for (int j = 0; j < KK; ++j)
            f[j] = *(const float4*)(sf + (r * TCOLS + wL + j) * CC + cg);

        #pragma unroll
        for (int oh = 0; oh < VH; ++oh) {
            const int i = r - oh;                    // kernel row
            if (i >= 0 && i < KK) {                  // compile-time after unroll
                const float* wp = skw + (oh * TW + wL) * (KK * KK) + i * KK;
                const float wg0 = wp[0], wg1 = wp[1], wg2 = wp[2],
                            wg3 = wp[3], wg4 = wp[4];
                acc[oh].x += f[0].x*wg0 + f[1].x*wg1 + f[2].x*wg2 + f[3].x*wg3 + f[4].x*wg4;
                acc[oh].y += f[0].y*wg0 + f[1].y*wg1 + f[2].y*wg2 + f[3].y*wg3 + f[4].y*wg4;
                acc[oh].z += f[0].z*wg0 + f[1].z*wg1 + f[2].z*wg2 + f[3].z*wg3 + f[4].z*wg4;
                acc[oh].w += f[0].w*wg0 + f[1].w*wg1 + f[2].w*wg2 + f[3].w*wg3 + f[4].w*wg4;
            }
        }
    }

    // ---- Coalesced stores: 8 rows x 1 KiB per wave. ----
    #pragma unroll
    for (int oh = 0; oh < VH; ++oh) {
        const size_t pix = (size_t)(b * HH + h0 + oh) * WW + (w0 + wL);
        *(float4*)(out + pix * CC + cg) = acc[oh];
    }
}

extern "C" void kernel_launch(void* const* d_in, const int* in_sizes, int n_in,
                              void* d_out, int out_size, void* d_ws, size_t ws_size,
                              hipStream_t stream) {
    const float* feat = (const float*)d_in[0];
    const float* kern = (const float*)d_in[1];
    const float* bias = (const float*)d_in[2];
    float* out = (float*)d_out;

    dim3 grid(BB * (HH / VH) * (WW / TW));  // 1024 blocks
    dim3 block(TPB);
    kpn_conv_kernel<<<grid, block, 0, stream>>>(feat, kern, bias, out);
}